// Round 10
// baseline (409.592 us; speedup 1.0000x reference)
//
#include <hip/hip_runtime.h>
#include <hip/hip_bf16.h>

// GraphSAGE-LSTM aggregator, MI355X (gfx950).  B=16384, T=25, D=128, U=128.
// R10 = R9 with compile fix only (__builtin_nontemporal_load rejects HIP
// float4 class type -> use clang ext_vector f32x4 for gather loads).
// R9 design vs R7 base:
//  - U fragments in REGISTERS (64 VGPR; 256-reg budget at (512,2) fits)
//  - xb,hb DOUBLE-BUFFERED in LDS: ONE barrier/step (26 vs 50)
//  - features gathered fp32 DIRECTLY from d_in (4x16B coalesced/thread,
//    bf16-convert at ds_write): prep_feats pass + 26MB writeback eliminated
//  - W loads (16) issued oldest, gather youngest, sched_barrier-pinned:
//    counted vmcnt waits for W never drain the in-flight gather
// LDS: xb 2x16K + hb 2x16K = 64 KiB.  256 blocks x 512 thr, 1 block/CU.
// ws layout (bf16 elems): [0,147456) = W,U,NW fragments.  ws_size 288 KB.

typedef __bf16 bf16;
typedef __bf16 bf16x8 __attribute__((ext_vector_type(8)));
typedef float f32x4 __attribute__((ext_vector_type(4)));

__device__ __forceinline__ float fast_sig(float x) {
  float e = __builtin_amdgcn_exp2f(-1.442695041f * x);
  return __builtin_amdgcn_rcpf(1.0f + e);
}
__device__ __forceinline__ float fast_tanh(float x) {
  float e = __builtin_amdgcn_exp2f(-2.885390082f * x);
  return (1.0f - e) * __builtin_amdgcn_rcpf(1.0f + e);
}
__device__ __forceinline__ f32x4 splat4(float x) {
  f32x4 v; v[0] = x; v[1] = x; v[2] = x; v[3] = x; return v;
}
__device__ __forceinline__ bf16x8 pack8(f32x4 a, f32x4 b) {
  bf16x8 v;
  v[0] = (bf16)a[0]; v[1] = (bf16)a[1]; v[2] = (bf16)a[2]; v[3] = (bf16)a[3];
  v[4] = (bf16)b[0]; v[5] = (bf16)b[1]; v[6] = (bf16)b[2]; v[7] = (bf16)b[3];
  return v;
}

// ---------------- prep: fragment-pack weights into ws (bf16) ----------------
// Fragment semantics (B operand of 16x16x32): lane supplies
//   B[k = kt*32 + (lane>>4)*8 + j][col], col = g*128 + ug*16 + (lane&15).
__global__ void prep_weights(const float* __restrict__ W, const float* __restrict__ U,
                             const float* __restrict__ NW, bf16* __restrict__ ws) {
  int idx = blockIdx.x * 256 + threadIdx.x;  // 576*256 = 147456 exactly
  if (idx < 131072) {
    const float* __restrict__ src = (idx < 65536) ? W : U;
    int r = idx & 65535;
    int f = r >> 9, lane = (r >> 3) & 63, j = r & 7;
    int kt = f & 3, g = (f >> 2) & 3, w = f >> 4;
    int k = kt * 32 + (lane >> 4) * 8 + j;
    int col = g * 128 + w * 16 + (lane & 15);
    ws[idx] = (bf16)src[k * 512 + col];
  } else {
    int r = idx - 131072;
    int f = r >> 9, lane = (r >> 3) & 63, j = r & 7;
    int kt = f & 3, w = f >> 2;
    int k = kt * 32 + (lane >> 4) * 8 + j;
    int col = w * 16 + (lane & 15);
    ws[idx] = (bf16)NW[k * 128 + col];
  }
}

// ---------------- fused LSTM aggregator ----------------
__global__ __launch_bounds__(512, 2)
void lstm_kernel(const float* __restrict__ feats, const int* __restrict__ node,
                 const int* __restrict__ neigh, const float* __restrict__ bias,
                 const bf16* __restrict__ wsf, float* __restrict__ out) {
  __shared__ char xb[2][16384];  // x tiles [64 rows][128] bf16, XOR-swizzled
  __shared__ char hb[2][16384];  // h tiles, same layout

  const int tid  = threadIdx.x;
  const int lane = tid & 63;
  const int ug   = tid >> 6;       // wave = unit group: units [ug*16, ug*16+16)
  const int l15  = lane & 15;
  const int lhi  = lane >> 4;
  const int b0   = blockIdx.x * 64;

  // Persistent U fragments in registers (64 VGPR), loaded once from ws.
  bf16x8 uf[4][4];
#pragma unroll
  for (int g = 0; g < 4; ++g)
#pragma unroll
    for (int kt = 0; kt < 4; ++kt)
      uf[g][kt] = *(const bf16x8*)(wsf + 65536 + (((ug * 4 + g) * 4 + kt) << 9) + (lane << 3));

  float bb[4];
#pragma unroll
  for (int g = 0; g < 4; ++g) bb[g] = bias[g * 128 + ug * 16 + l15];

  f32x4 cc[4];  // cell state: row = m*16 + lhi*4 + r, unit = ug*16 + l15
#pragma unroll
  for (int m = 0; m < 4; ++m) cc[m] = splat4(0.0f);

  // Gather mapping: thread covers row gr, 16 consecutive feature elems (fp32).
  const int gr = tid >> 3;          // 0..63
  const int gq = tid & 7;           // 16-elem chunk within row
  const int xsw = (gr & 7) << 4;
  const int xbase = gr * 256 + gq * 32;
  const int rbase = (b0 + gr) * 25;

  // x_0 (fp32 gather, bf16 convert at LDS write)
  {
    int ni = neigh[rbase];
    const f32x4* gs = (const f32x4*)(feats + (size_t)ni * 128 + gq * 16);
    f32x4 f0 = __builtin_nontemporal_load(gs + 0);
    f32x4 f1 = __builtin_nontemporal_load(gs + 1);
    f32x4 f2 = __builtin_nontemporal_load(gs + 2);
    f32x4 f3 = __builtin_nontemporal_load(gs + 3);
    *(bf16x8*)(xb[0] + (xbase ^ xsw))        = pack8(f0, f1);
    *(bf16x8*)(xb[0] + ((xbase + 16) ^ xsw)) = pack8(f2, f3);
  }
  int ni_next = neigh[rbase + 1];
  __syncthreads();

  f32x4 acc[4][4];                 // [gate][Mtile]
  const int asw = (l15 & 7) << 4;  // A-frag row swizzle (row&7 == l15&7)

#pragma unroll 1
  for (int t = 0; t < 24; ++t) {
    const int p = t & 1;
    const char* xrd = xb[p];
    const char* hrd = hb[p];
    char*       xwr = xb[p ^ 1];
    char*       hwr = hb[p ^ 1];

    int ni = ni_next;
    ni_next = (t < 23) ? neigh[rbase + t + 2] : node[b0 + gr];

    // 1. ALL 16 W-frag loads first (oldest in vmcnt queue, L2-resident)
    bf16x8 wf[4][4];
#pragma unroll
    for (int g = 0; g < 4; ++g)
#pragma unroll
      for (int kt = 0; kt < 4; ++kt)
        wf[g][kt] = *(const bf16x8*)(wsf + (((ug * 4 + g) * 4 + kt) << 9) + (lane << 3));
    __builtin_amdgcn_sched_barrier(0);

    // 2. gather x_{t+1} fp32 (youngest; stays in flight under MFMA phase)
    const f32x4* gs = (const f32x4*)(feats + (size_t)ni * 128 + gq * 16);
    f32x4 f0 = __builtin_nontemporal_load(gs + 0);
    f32x4 f1 = __builtin_nontemporal_load(gs + 1);
    f32x4 f2 = __builtin_nontemporal_load(gs + 2);
    f32x4 f3 = __builtin_nontemporal_load(gs + 3);
    __builtin_amdgcn_sched_barrier(0);

    // 3. acc init with bias
#pragma unroll
    for (int g = 0; g < 4; ++g) {
      f32x4 bi = splat4(bb[g]);
#pragma unroll
      for (int m = 0; m < 4; ++m) acc[g][m] = bi;
    }

    // 4. MFMA phase: per kt, 4 xa (+4 ha) ds_reads; x@W then h@U (U in regs)
#pragma unroll
    for (int kt = 0; kt < 4; ++kt) {
      bf16x8 xa[4];
#pragma unroll
      for (int m = 0; m < 4; ++m)
        xa[m] = *(const bf16x8*)(xrd + (((m * 16 + l15) * 256 + (kt * 4 + lhi) * 16) ^ asw));
#pragma unroll
      for (int g = 0; g < 4; ++g)
#pragma unroll
        for (int m = 0; m < 4; ++m)
          acc[g][m] = __builtin_amdgcn_mfma_f32_16x16x32_bf16(xa[m], wf[g][kt], acc[g][m], 0, 0, 0);
      if (t > 0) {
        bf16x8 ha[4];
#pragma unroll
        for (int m = 0; m < 4; ++m)
          ha[m] = *(const bf16x8*)(hrd + (((m * 16 + l15) * 256 + (kt * 4 + lhi) * 16) ^ asw));
#pragma unroll
        for (int g = 0; g < 4; ++g)
#pragma unroll
          for (int m = 0; m < 4; ++m)
            acc[g][m] = __builtin_amdgcn_mfma_f32_16x16x32_bf16(ha[m], uf[g][kt], acc[g][m], 0, 0, 0);
      }
    }

    // 5. write x_{t+1} into the ALTERNATE buffer (no race with readers of p)
    *(bf16x8*)(xwr + (xbase ^ xsw))        = pack8(f0, f1);
    *(bf16x8*)(xwr + ((xbase + 16) ^ xsw)) = pack8(f2, f3);

    // 6. gates (wave-private) -> h into alternate buffer
#pragma unroll
    for (int m = 0; m < 4; ++m)
#pragma unroll
      for (int r = 0; r < 4; ++r) {
        float iv = fast_sig(acc[0][m][r]);
        float fv = fast_sig(acc[1][m][r]);
        float gv = fast_tanh(acc[2][m][r]);
        float ov = fast_sig(acc[3][m][r]);
        float cv = fv * cc[m][r] + iv * gv;
        cc[m][r] = cv;
        float hv = ov * fast_tanh(cv);
        int row = m * 16 + lhi * 4 + r;
        *(bf16*)(hwr + ((row * 256 + (ug * 16 + l15) * 2) ^ ((row & 7) << 4))) = (bf16)hv;
      }

    __syncthreads();  // single barrier per step
  }

  // ----- step 24 (peeled): p=0; gather = NODE features -----
  float hl[4][4];
  {
    const char* xrd = xb[0];
    const char* hrd = hb[0];

    bf16x8 wf[4][4];
#pragma unroll
    for (int g = 0; g < 4; ++g)
#pragma unroll
      for (int kt = 0; kt < 4; ++kt)
        wf[g][kt] = *(const bf16x8*)(wsf + (((ug * 4 + g) * 4 + kt) << 9) + (lane << 3));
    __builtin_amdgcn_sched_barrier(0);

    const f32x4* gs = (const f32x4*)(feats + (size_t)ni_next * 128 + gq * 16);
    f32x4 f0 = __builtin_nontemporal_load(gs + 0);
    f32x4 f1 = __builtin_nontemporal_load(gs + 1);
    f32x4 f2 = __builtin_nontemporal_load(gs + 2);
    f32x4 f3 = __builtin_nontemporal_load(gs + 3);
    __builtin_amdgcn_sched_barrier(0);

#pragma unroll
    for (int g = 0; g < 4; ++g) {
      f32x4 bi = splat4(bb[g]);
#pragma unroll
      for (int m = 0; m < 4; ++m) acc[g][m] = bi;
    }
#pragma unroll
    for (int kt = 0; kt < 4; ++kt) {
      bf16x8 xa[4], ha[4];
#pragma unroll
      for (int m = 0; m < 4; ++m) {
        xa[m] = *(const bf16x8*)(xrd + (((m * 16 + l15) * 256 + (kt * 4 + lhi) * 16) ^ asw));
        ha[m] = *(const bf16x8*)(hrd + (((m * 16 + l15) * 256 + (kt * 4 + lhi) * 16) ^ asw));
      }
#pragma unroll
      for (int g = 0; g < 4; ++g)
#pragma unroll
        for (int m = 0; m < 4; ++m) {
          acc[g][m] = __builtin_amdgcn_mfma_f32_16x16x32_bf16(xa[m], wf[g][kt], acc[g][m], 0, 0, 0);
          acc[g][m] = __builtin_amdgcn_mfma_f32_16x16x32_bf16(ha[m], uf[g][kt], acc[g][m], 0, 0, 0);
        }
    }

    // node feats -> xb[1] for the epilogue GEMM
    *(bf16x8*)(xb[1] + (xbase ^ xsw))        = pack8(f0, f1);
    *(bf16x8*)(xb[1] + ((xbase + 16) ^ xsw)) = pack8(f2, f3);

#pragma unroll
    for (int m = 0; m < 4; ++m)
#pragma unroll
      for (int r = 0; r < 4; ++r) {
        float iv = fast_sig(acc[0][m][r]);
        float fv = fast_sig(acc[1][m][r]);
        float gv = fast_tanh(acc[2][m][r]);
        float ov = fast_sig(acc[3][m][r]);
        float cv = fv * cc[m][r] + iv * gv;
        hl[m][r] = ov * fast_tanh(cv);
      }
    __syncthreads();  // node feats visible in xb[1]
  }

  // ----- from_self = node_feat @ node_weights; out = relu((s + h)/2) -----
  {
    f32x4 accs[4];
#pragma unroll
    for (int m = 0; m < 4; ++m) accs[m] = splat4(0.0f);
#pragma unroll
    for (int kt = 0; kt < 4; ++kt) {
      bf16x8 nwf = *(const bf16x8*)(wsf + 131072 + ((ug * 4 + kt) << 9) + (lane << 3));
      bf16x8 xa[4];
#pragma unroll
      for (int m = 0; m < 4; ++m)
        xa[m] = *(const bf16x8*)(xb[1] + (((m * 16 + l15) * 256 + (kt * 4 + lhi) * 16) ^ asw));
#pragma unroll
      for (int m = 0; m < 4; ++m)
        accs[m] = __builtin_amdgcn_mfma_f32_16x16x32_bf16(xa[m], nwf, accs[m], 0, 0, 0);
    }
#pragma unroll
    for (int m = 0; m < 4; ++m)
#pragma unroll
      for (int r = 0; r < 4; ++r) {
        int row = m * 16 + lhi * 4 + r;
        float v = (accs[m][r] + hl[m][r]) * 0.5f;
        __builtin_nontemporal_store(v > 0.0f ? v : 0.0f,
                                    out + (b0 + row) * 128 + ug * 16 + l15);
      }
  }
}

extern "C" void kernel_launch(void* const* d_in, const int* in_sizes, int n_in,
                              void* d_out, int out_size, void* d_ws, size_t ws_size,
                              hipStream_t stream) {
  const float* feats = (const float*)d_in[0];   // 100000 x 128
  const int*   node  = (const int*)d_in[1];     // 16384 x 1
  const int*   neigh = (const int*)d_in[2];     // 16384 x 25
  const float* nw    = (const float*)d_in[3];   // 128 x 128
  const float* W     = (const float*)d_in[4];   // 128 x 512
  const float* U     = (const float*)d_in[5];   // 128 x 512
  const float* b     = (const float*)d_in[6];   // 512
  bf16* ws = (bf16*)d_ws;                       // needs 288 KB
  float* out = (float*)d_out;                   // 16384 x 128

  prep_weights<<<576, 256, 0, stream>>>(W, U, nw, ws);
  lstm_kernel<<<256, 512, 0, stream>>>(feats, node, neigh, b, ws, out);
}